// Round 1
// baseline (3271.311 us; speedup 1.0000x reference)
//
#include <hip/hip_runtime.h>

#define T_ 512
#define B_ 256
#define D_ 256
#define H_ 256

typedef short s16x8 __attribute__((ext_vector_type(8)));
typedef float f32x4 __attribute__((ext_vector_type(4)));

static __device__ __forceinline__ unsigned short f2bf(float f){
  unsigned u = __float_as_uint(f);
  u += 0x7FFFu + ((u >> 16) & 1u);
  return (unsigned short)(u >> 16);
}
static __device__ __forceinline__ float bf2f(unsigned short h){
  return __uint_as_float(((unsigned)h) << 16);
}
static __device__ __forceinline__ unsigned pk2(float a, float b){
  return (unsigned)f2bf(a) | ((unsigned)f2bf(b) << 16);
}
static __device__ __forceinline__ float sigf(float x){
  return __builtin_amdgcn_rcpf(1.0f + __expf(-x));
}
static __device__ __forceinline__ float tanhf_(float x){
  return 1.0f - 2.0f * __builtin_amdgcn_rcpf(__expf(2.0f * x) + 1.0f);
}

// ---------------- kernel 0: split W into Wx / Wh bf16 copies ----------------
__global__ void k_cast(const float* __restrict__ W,
                       unsigned short* __restrict__ Wxb,
                       unsigned short* __restrict__ Whb)
{
  const int i = blockIdx.x * 256 + threadIdx.x;   // 0 .. 1024*256-1
  const int row = i >> 8;
  const int k = i & 255;
  Wxb[i] = f2bf(W[(size_t)row * 512 + k]);
  Whb[i] = f2bf(W[(size_t)row * 512 + 256 + k]);
}

// ---------------- phase 1: zx = Wx * x^T + b, stored in MFMA C-fragment layout
// M = 1024 rows (g,q), N = (t,b) flat, K = 256.
// zx layout: [n16tile(chunk-local)][m16tile 0..63][lane 0..63][4 bf16]  (512B per tile)
__global__ __launch_bounds__(512, 2) void k_phase1(
    const unsigned short* __restrict__ Wxb,
    const float* __restrict__ x,
    const float* __restrict__ bias,
    unsigned short* __restrict__ zxf,
    int t0)
{
  extern __shared__ char smem[];          // [0,64K): A = Wx tile, [64K,128K): B = x tile (bf16, swizzled)
  char* Bs = smem + 65536;
  const int tid  = threadIdx.x;
  const int lane = tid & 63;
  const int wid  = tid >> 6;
  const int r16  = lane >> 4;
  const int c16  = lane & 15;
  const int ntile = blockIdx.x;
  const int mbase = blockIdx.y * 128;
  const size_t nbase = (size_t)t0 * 256 + (size_t)ntile * 128;

  // stage A: 128 rows of Wxb (64KB), swizzled
#pragma unroll
  for (int r = 0; r < 8; ++r){
    const int ch = r * 512 + tid;
    const int row = ch >> 5;
    const int cc = ch & 31;
    uint4 v = *(const uint4*)(Wxb + (size_t)(mbase + row) * 256 + cc * 8);
    *(uint4*)(smem + row * 512 + ((cc * 16) ^ ((row & 7) << 4))) = v;
  }
  // stage B: 128 rows of x (f32 -> bf16), swizzled
#pragma unroll
  for (int r = 0; r < 8; ++r){
    const int ch = r * 512 + tid;
    const int row = ch >> 5;
    const int cc = ch & 31;
    const float* xp = x + (nbase + row) * 256 + cc * 8;
    const float4 a  = *(const float4*)(xp);
    const float4 b2 = *(const float4*)(xp + 4);
    uint4 w;
    w.x = pk2(a.x, a.y);   w.y = pk2(a.z, a.w);
    w.z = pk2(b2.x, b2.y); w.w = pk2(b2.z, b2.w);
    *(uint4*)(Bs + row * 512 + ((cc * 16) ^ ((row & 7) << 4))) = w;
  }
  __syncthreads();

  const int wm = wid >> 2;   // 0..1
  const int wn = wid & 3;    // 0..3
  f32x4 acc[4][2];
#pragma unroll
  for (int mt = 0; mt < 4; ++mt)
#pragma unroll
    for (int i = 0; i < 4; ++i){
      const float bv = bias[mbase + wm * 64 + mt * 16 + r16 * 4 + i];
      acc[mt][0][i] = bv;
      acc[mt][1][i] = bv;
    }

#pragma unroll
  for (int kc = 0; kc < 8; ++kc){
    s16x8 bf[2];
#pragma unroll
    for (int nt = 0; nt < 2; ++nt){
      const int row = wn * 32 + nt * 16 + c16;
      bf[nt] = *(const s16x8*)(Bs + row * 512 + ((kc * 64 + r16 * 16) ^ ((row & 7) << 4)));
    }
#pragma unroll
    for (int mt = 0; mt < 4; ++mt){
      const int row = wm * 64 + mt * 16 + c16;
      const s16x8 af = *(const s16x8*)(smem + row * 512 + ((kc * 64 + r16 * 16) ^ ((row & 7) << 4)));
#pragma unroll
      for (int nt = 0; nt < 2; ++nt)
        acc[mt][nt] = __builtin_amdgcn_mfma_f32_16x16x32_bf16(af, bf[nt], acc[mt][nt], 0, 0, 0);
    }
  }

#pragma unroll
  for (int mt = 0; mt < 4; ++mt)
#pragma unroll
    for (int nt = 0; nt < 2; ++nt){
      const int m16 = (mbase >> 4) + wm * 4 + mt;
      const size_t n16 = (size_t)ntile * 8 + wn * 2 + nt;   // chunk-local (t,b)/16
      uint2 p;
      p.x = pk2(acc[mt][nt][0], acc[mt][nt][1]);
      p.y = pk2(acc[mt][nt][2], acc[mt][nt][3]);
      *(uint2*)((char*)zxf + (n16 * 64 + m16) * 512 + lane * 8) = p;
    }
}

// ---------------- phase 2: the recurrence. 16 wgs, one per 16-batch tile.
// Wh resident: rows 0..767 (gates 0..2) in VGPR fragments, rows 768..1023 (gate 3) in LDS.
__global__ __launch_bounds__(512, 2) void k_phase2(
    const unsigned short* __restrict__ Whb,
    const unsigned short* __restrict__ zxf,
    float* __restrict__ out,
    unsigned short* __restrict__ sh,
    float* __restrict__ sc,
    int t0, int TC)
{
  extern __shared__ char smem[];     // [0,128K): Wh gate-3 tiles (16 x 8KB), [128K,136K): h buffer
  char* hLb = smem + 131072;
  const int tid  = threadIdx.x;
  const int lane = tid & 63;
  const int wid  = tid >> 6;
  const int r16  = lane >> 4;
  const int c16  = lane & 15;
  const int bt   = blockIdx.x;
  const int b    = bt * 16 + c16;

  // register-resident Wh A-fragments: gates 0..2, tiles (wid*2+s), 8 k-chunks
  s16x8 wf[6][8];
#pragma unroll
  for (int g = 0; g < 3; ++g)
#pragma unroll
    for (int s = 0; s < 2; ++s){
      const int row = (g * 16 + wid * 2 + s) * 16 + c16;
      const unsigned short* wp = Whb + (size_t)row * 256 + r16 * 8;
#pragma unroll
      for (int kc = 0; kc < 8; ++kc)
        wf[g * 2 + s][kc] = *(const s16x8*)(wp + kc * 32);
    }
  // gate-3 tiles -> LDS (swizzled), each wave stages its own two tiles
#pragma unroll
  for (int s = 0; s < 2; ++s){
    const int rt = 48 + wid * 2 + s;
#pragma unroll
    for (int r = 0; r < 8; ++r){
      const int ch = r * 64 + lane;
      const int rr = ch >> 5;
      const int cc = ch & 31;
      uint4 v = *(const uint4*)(Whb + (size_t)(rt * 16 + rr) * 256 + cc * 8);
      *(uint4*)(smem + (wid * 2 + s) * 8192 + rr * 512 + ((cc * 16) ^ ((rr & 7) << 4))) = v;
    }
  }

  float cst[2][4];
  if (t0 == 0){
#pragma unroll
    for (int s = 0; s < 2; ++s)
#pragma unroll
      for (int i = 0; i < 4; ++i) cst[s][i] = 0.0f;
    *(uint4*)(hLb + tid * 16) = make_uint4(0, 0, 0, 0);
  } else {
#pragma unroll
    for (int s = 0; s < 2; ++s){
      const int q0 = (wid * 2 + s) * 16 + r16 * 4;
      const float4 cv = *(const float4*)(sc + (size_t)b * 256 + q0);
      cst[s][0] = cv.x; cst[s][1] = cv.y; cst[s][2] = cv.z; cst[s][3] = cv.w;
    }
    const int brow = tid >> 5;
    const int cc = tid & 31;
    uint4 v = *(const uint4*)((const char*)sh + (size_t)(bt * 16 + brow) * 512 + cc * 16);
    *(uint4*)(hLb + brow * 512 + ((cc * 16) ^ ((brow & 7) << 4))) = v;
  }
  __syncthreads();

  unsigned hpack[2][2];

  for (int t = t0; t < t0 + TC; ++t){
    const char* zxt = (const char*)zxf + ((size_t)(t - t0) * 16 + bt) * 64 * 512 + lane * 8;
#pragma unroll
    for (int s = 0; s < 2; ++s){
      f32x4 acc[4];
#pragma unroll
      for (int g = 0; g < 4; ++g){
        const int rt = g * 16 + wid * 2 + s;
        const uint2 zv = *(const uint2*)(zxt + rt * 512);
        acc[g][0] = bf2f((unsigned short)(zv.x & 0xFFFFu));
        acc[g][1] = bf2f((unsigned short)(zv.x >> 16));
        acc[g][2] = bf2f((unsigned short)(zv.y & 0xFFFFu));
        acc[g][3] = bf2f((unsigned short)(zv.y >> 16));
      }
#pragma unroll
      for (int kc = 0; kc < 8; ++kc){
        const s16x8 hv = *(const s16x8*)(hLb + c16 * 512 + ((kc * 64 + r16 * 16) ^ ((c16 & 7) << 4)));
        acc[0] = __builtin_amdgcn_mfma_f32_16x16x32_bf16(wf[0 + s][kc], hv, acc[0], 0, 0, 0);
        acc[1] = __builtin_amdgcn_mfma_f32_16x16x32_bf16(wf[2 + s][kc], hv, acc[1], 0, 0, 0);
        acc[2] = __builtin_amdgcn_mfma_f32_16x16x32_bf16(wf[4 + s][kc], hv, acc[2], 0, 0, 0);
        const s16x8 av = *(const s16x8*)(smem + (wid * 2 + s) * 8192 + c16 * 512 +
                                         ((kc * 64 + r16 * 16) ^ ((c16 & 7) << 4)));
        acc[3] = __builtin_amdgcn_mfma_f32_16x16x32_bf16(av, hv, acc[3], 0, 0, 0);
      }
      const int q0 = (wid * 2 + s) * 16 + r16 * 4;
      float ho[4];
#pragma unroll
      for (int i = 0; i < 4; ++i){
        const float fg = sigf(__cosf(acc[0][i]));
        const float ig = sigf(__cosf(acc[1][i]));
        const float gg = tanhf_(__cosf(acc[2][i]));
        const float og = sigf(__cosf(acc[3][i]));
        const float cn = fg * cst[s][i] + ig * gg;
        cst[s][i] = cn;
        ho[i] = og * tanhf_(cn);
      }
      *(float4*)(out + ((size_t)t * B_ + b) * H_ + q0) = make_float4(ho[0], ho[1], ho[2], ho[3]);
      hpack[s][0] = pk2(ho[0], ho[1]);
      hpack[s][1] = pk2(ho[2], ho[3]);
      if (t == T_ - 1){
        float* hl = out + (size_t)T_ * B_ * H_;
        *(float4*)(hl + (size_t)b * H_ + q0) = make_float4(ho[0], ho[1], ho[2], ho[3]);
        float* cl = hl + (size_t)B_ * H_;
        *(float4*)(cl + (size_t)b * H_ + q0) = make_float4(cst[s][0], cst[s][1], cst[s][2], cst[s][3]);
      }
    }
    __syncthreads();   // all reads of h done
#pragma unroll
    for (int s = 0; s < 2; ++s){
      const int q0 = (wid * 2 + s) * 16 + r16 * 4;
      *(uint2*)(hLb + c16 * 512 + ((q0 * 2) ^ ((c16 & 7) << 4))) = make_uint2(hpack[s][0], hpack[s][1]);
    }
    __syncthreads();   // h ready for next step
  }

  if (t0 + TC < T_){
#pragma unroll
    for (int s = 0; s < 2; ++s){
      const int q0 = (wid * 2 + s) * 16 + r16 * 4;
      *(uint2*)((char*)sh + (size_t)b * 512 + q0 * 2) = make_uint2(hpack[s][0], hpack[s][1]);
      *(float4*)(sc + (size_t)b * 256 + q0) = make_float4(cst[s][0], cst[s][1], cst[s][2], cst[s][3]);
    }
  }
}

extern "C" void kernel_launch(void* const* d_in, const int* in_sizes, int n_in,
                              void* d_out, int out_size, void* d_ws, size_t ws_size,
                              hipStream_t stream)
{
  const float* x    = (const float*)d_in[0];   // [T,B,D] f32
  const float* W    = (const float*)d_in[1];   // [4,H,D+H] f32
  const float* bias = (const float*)d_in[2];   // [4,H] f32
  float* out = (float*)d_out;                  // outputs | h_last | c_last (f32)

  char* ws = (char*)d_ws;
  unsigned short* Wxb = (unsigned short*)(ws);
  unsigned short* Whb = (unsigned short*)(ws + 524288);
  unsigned short* sh  = (unsigned short*)(ws + 1048576);          // h state [256][256] bf16
  float*          sc  = (float*)(ws + 1179648);                   // c state [256][256] f32
  unsigned short* zxf = (unsigned short*)(ws + 1441792);          // zx fragment buffer

  (void)hipFuncSetAttribute((const void*)k_phase1, hipFuncAttributeMaxDynamicSharedMemorySize, 131072);
  (void)hipFuncSetAttribute((const void*)k_phase2, hipFuncAttributeMaxDynamicSharedMemorySize, 139264);

  // largest time-chunk whose zx buffer fits the workspace
  int TC = 8;
  const int cands[6] = {512, 256, 128, 64, 32, 16};
  for (int i = 0; i < 6; ++i){
    if (1441792ull + (unsigned long long)cands[i] * 524288ull <= (unsigned long long)ws_size){
      TC = cands[i];
      break;
    }
  }

  k_cast<<<1024, 256, 0, stream>>>(W, Wxb, Whb);
  for (int t0 = 0; t0 < T_; t0 += TC){
    k_phase1<<<dim3(TC * 2, 8, 1), 512, 131072, stream>>>(Wxb, x, bias, zxf, t0);
    k_phase2<<<dim3(16, 1, 1), 512, 139264, stream>>>(Whb, zxf, out, sh, sc, t0, TC);
  }
}

// Round 2
// 2915.907 us; speedup vs baseline: 1.1219x; 1.1219x over previous
//
#include <hip/hip_runtime.h>

#define T_ 512
#define B_ 256
#define D_ 256
#define H_ 256

typedef short s16x8 __attribute__((ext_vector_type(8)));
typedef float f32x4 __attribute__((ext_vector_type(4)));

static __device__ __forceinline__ unsigned short f2bf(float f){
  unsigned u = __float_as_uint(f);
  u += 0x7FFFu + ((u >> 16) & 1u);
  return (unsigned short)(u >> 16);
}
static __device__ __forceinline__ float bf2f(unsigned short h){
  return __uint_as_float(((unsigned)h) << 16);
}
static __device__ __forceinline__ unsigned pk2(float a, float b){
  return (unsigned)f2bf(a) | ((unsigned)f2bf(b) << 16);
}
static __device__ __forceinline__ float sigf(float x){
  return __builtin_amdgcn_rcpf(1.0f + __expf(-x));
}
static __device__ __forceinline__ float tanhf_(float x){
  return 1.0f - 2.0f * __builtin_amdgcn_rcpf(__expf(2.0f * x) + 1.0f);
}

// ---------------- kernel 0a: split W into Wx / Wh bf16 copies ----------------
__global__ void k_cast(const float* __restrict__ W,
                       unsigned short* __restrict__ Wxb,
                       unsigned short* __restrict__ Whb)
{
  const int i = blockIdx.x * 256 + threadIdx.x;   // 0 .. 1024*256-1
  const int row = i >> 8;
  const int k = i & 255;
  Wxb[i] = f2bf(W[(size_t)row * 512 + k]);
  Whb[i] = f2bf(W[(size_t)row * 512 + 256 + k]);
}

// ---------------- kernel 0b: cast x (T*B*D f32) -> bf16 ----------------
__global__ void k_cast_x(const float* __restrict__ x,
                         unsigned short* __restrict__ xb)
{
  const size_t i = ((size_t)blockIdx.x * 256 + threadIdx.x) * 8;
  const float4 a = *(const float4*)(x + i);
  const float4 b = *(const float4*)(x + i + 4);
  uint4 w;
  w.x = pk2(a.x, a.y);  w.y = pk2(a.z, a.w);
  w.z = pk2(b.x, b.y);  w.w = pk2(b.z, b.w);
  *(uint4*)(xb + i) = w;
}

// ---------------- phase 1: zx = Wx * x^T + b, stored in MFMA C-fragment layout
// M = 1024 rows (g,q), N = (t,b) flat, K = 256.  A-tile resident, 16 n-tiles/WG.
// zx layout: [n16tile(chunk-local)][m16tile 0..63][lane 0..63][4 bf16]  (512B per tile)
__global__ __launch_bounds__(512, 2) void k_phase1(
    const unsigned short* __restrict__ Wxb,
    const unsigned short* __restrict__ xb,
    const float* __restrict__ bias,
    unsigned short* __restrict__ zxf,
    int t0)
{
  extern __shared__ char smem[];          // [0,64K): A = Wx tile, [64K,128K): B = x tile (bf16, swizzled)
  char* Bs = smem + 65536;
  const int tid  = threadIdx.x;
  const int lane = tid & 63;
  const int wid  = tid >> 6;
  const int r16  = lane >> 4;
  const int c16  = lane & 15;
  const int wm = wid >> 2;   // 0..1
  const int wn = wid & 3;    // 0..3
  const int mbase  = blockIdx.y * 128;
  const int ntile0 = blockIdx.x * 16;
  const size_t nbase = (size_t)t0 * 256 + (size_t)ntile0 * 128;

  // stage A once: 128 rows of Wxb (64KB), swizzled
#pragma unroll
  for (int r = 0; r < 8; ++r){
    const int ch = r * 512 + tid;
    const int row = ch >> 5;
    const int cc = ch & 31;
    uint4 v = *(const uint4*)(Wxb + (size_t)(mbase + row) * 256 + cc * 8);
    *(uint4*)(smem + row * 512 + ((cc * 16) ^ ((row & 7) << 4))) = v;
  }
  // bias in regs
  float bv[4][4];
#pragma unroll
  for (int mt = 0; mt < 4; ++mt)
#pragma unroll
    for (int i = 0; i < 4; ++i)
      bv[mt][i] = bias[mbase + wm * 64 + mt * 16 + r16 * 4 + i];

  // prefetch B tile 0 into regs
  uint4 pb[8];
#pragma unroll
  for (int r = 0; r < 8; ++r){
    const int ch = r * 512 + tid;
    const int row = ch >> 5;
    const int cc = ch & 31;
    pb[r] = *(const uint4*)(xb + (nbase + row) * 256 + cc * 8);
  }

  for (int it = 0; it < 16; ++it){
    __syncthreads();   // previous iteration's reads done (it=0: nothing; also orders A writes)
#pragma unroll
    for (int r = 0; r < 8; ++r){
      const int ch = r * 512 + tid;
      const int row = ch >> 5;
      const int cc = ch & 31;
      *(uint4*)(Bs + row * 512 + ((cc * 16) ^ ((row & 7) << 4))) = pb[r];
    }
    __syncthreads();   // B visible
    if (it < 15){
      const size_t nb = nbase + (size_t)(it + 1) * 128;
#pragma unroll
      for (int r = 0; r < 8; ++r){
        const int ch = r * 512 + tid;
        const int row = ch >> 5;
        const int cc = ch & 31;
        pb[r] = *(const uint4*)(xb + (nb + row) * 256 + cc * 8);
      }
    }

    f32x4 acc[4][2];
#pragma unroll
    for (int mt = 0; mt < 4; ++mt)
#pragma unroll
      for (int i = 0; i < 4; ++i){
        acc[mt][0][i] = bv[mt][i];
        acc[mt][1][i] = bv[mt][i];
      }

#pragma unroll
    for (int kc = 0; kc < 8; ++kc){
      s16x8 bf[2];
#pragma unroll
      for (int nt = 0; nt < 2; ++nt){
        const int row = wn * 32 + nt * 16 + c16;
        bf[nt] = *(const s16x8*)(Bs + row * 512 + ((kc * 64 + r16 * 16) ^ ((row & 7) << 4)));
      }
#pragma unroll
      for (int mt = 0; mt < 4; ++mt){
        const int row = wm * 64 + mt * 16 + c16;
        const s16x8 af = *(const s16x8*)(smem + row * 512 + ((kc * 64 + r16 * 16) ^ ((row & 7) << 4)));
#pragma unroll
        for (int nt = 0; nt < 2; ++nt)
          acc[mt][nt] = __builtin_amdgcn_mfma_f32_16x16x32_bf16(af, bf[nt], acc[mt][nt], 0, 0, 0);
      }
    }

    const int ntile = ntile0 + it;
#pragma unroll
    for (int mt = 0; mt < 4; ++mt)
#pragma unroll
      for (int ss = 0; ss < 2; ++ss){
        const int m16 = (mbase >> 4) + wm * 4 + mt;
        const size_t n16 = (size_t)ntile * 8 + wn * 2 + ss;   // chunk-local (t,b)/16
        uint2 p;
        p.x = pk2(acc[mt][ss][0], acc[mt][ss][1]);
        p.y = pk2(acc[mt][ss][2], acc[mt][ss][3]);
        *(uint2*)((char*)zxf + (n16 * 64 + m16) * 512 + lane * 8) = p;
      }
  }
}

// ---------------- phase 2: the recurrence. 16 wgs, one per 16-batch tile.
// Wh resident: rows 0..767 (gates 0..2) in VGPR fragments, rows 768..1023 (gate 3) in LDS.
// LDS: [0,128K) gate-3 tiles; [128K,136K) hbuf0; [136K,144K) hbuf1.
// One barrier per step (double-buffered h). zx register-prefetched one step ahead.
__global__ __launch_bounds__(512, 2) void k_phase2(
    const unsigned short* __restrict__ Whb,
    const unsigned short* __restrict__ zxf,
    float* __restrict__ out,
    unsigned short* __restrict__ sh,
    float* __restrict__ sc,
    int t0, int TC)
{
  extern __shared__ char smem[];
  const int tid  = threadIdx.x;
  const int lane = tid & 63;
  const int wid  = tid >> 6;
  const int r16  = lane >> 4;
  const int c16  = lane & 15;
  const int bt   = blockIdx.x;
  const int b    = bt * 16 + c16;

  // register-resident Wh A-fragments: gates 0..2, tiles (wid*2+s), 8 k-chunks
  s16x8 wf[6][8];
#pragma unroll
  for (int g = 0; g < 3; ++g)
#pragma unroll
    for (int s = 0; s < 2; ++s){
      const int row = (g * 16 + wid * 2 + s) * 16 + c16;
      const unsigned short* wp = Whb + (size_t)row * 256 + r16 * 8;
#pragma unroll
      for (int kc = 0; kc < 8; ++kc)
        wf[g * 2 + s][kc] = *(const s16x8*)(wp + kc * 32);
    }
  // gate-3 tiles -> LDS (swizzled), each wave stages its own two tiles
#pragma unroll
  for (int s = 0; s < 2; ++s){
    const int rt = 48 + wid * 2 + s;
#pragma unroll
    for (int r = 0; r < 8; ++r){
      const int ch = r * 64 + lane;
      const int rr = ch >> 5;
      const int cc = ch & 31;
      uint4 v = *(const uint4*)(Whb + (size_t)(rt * 16 + rr) * 256 + cc * 8);
      *(uint4*)(smem + (wid * 2 + s) * 8192 + rr * 512 + ((cc * 16) ^ ((rr & 7) << 4))) = v;
    }
  }

  float cst[2][4];
  char* hb0 = smem + 131072;
  if (t0 == 0){
#pragma unroll
    for (int s = 0; s < 2; ++s)
#pragma unroll
      for (int i = 0; i < 4; ++i) cst[s][i] = 0.0f;
    *(uint4*)(hb0 + tid * 16) = make_uint4(0, 0, 0, 0);
  } else {
#pragma unroll
    for (int s = 0; s < 2; ++s){
      const int q0 = (wid * 2 + s) * 16 + r16 * 4;
      const float4 cv = *(const float4*)(sc + (size_t)b * 256 + q0);
      cst[s][0] = cv.x; cst[s][1] = cv.y; cst[s][2] = cv.z; cst[s][3] = cv.w;
    }
    const int brow = tid >> 5;
    const int cc = tid & 31;
    uint4 v = *(const uint4*)((const char*)sh + (size_t)(bt * 16 + brow) * 512 + cc * 16);
    *(uint4*)(hb0 + brow * 512 + ((cc * 16) ^ ((brow & 7) << 4))) = v;
  }
  __syncthreads();

  const char* zlane = (const char*)zxf + (size_t)lane * 8;
  // preload zc for tt = 0
  uint2 zc[2][4];
#pragma unroll
  for (int s = 0; s < 2; ++s)
#pragma unroll
    for (int g = 0; g < 4; ++g)
      zc[s][g] = *(const uint2*)(zlane + ((size_t)bt * 64 + g * 16 + wid * 2 + s) * 512);

  for (int t = t0; t < t0 + TC; ++t){
    const int tt = t - t0;
    const char* hread = smem + 131072 + ((tt & 1) << 13);
    char*      hwrite = smem + 131072 + (((tt & 1) ^ 1) << 13);
    const int ttn = (tt + 1 < TC) ? (tt + 1) : tt;
    const size_t znoff = ((size_t)ttn * 16 + bt) * 64 * 512;
    uint2 zn[2][4];

#pragma unroll
    for (int s = 0; s < 2; ++s){
      f32x4 acc[4];
#pragma unroll
      for (int g = 0; g < 4; ++g){
        acc[g][0] = bf2f((unsigned short)(zc[s][g].x & 0xFFFFu));
        acc[g][1] = bf2f((unsigned short)(zc[s][g].x >> 16));
        acc[g][2] = bf2f((unsigned short)(zc[s][g].y & 0xFFFFu));
        acc[g][3] = bf2f((unsigned short)(zc[s][g].y >> 16));
      }
      // prefetch next step's zx for this s (zc[s] is dead now)
#pragma unroll
      for (int g = 0; g < 4; ++g)
        zn[s][g] = *(const uint2*)(zlane + znoff + (size_t)(g * 16 + wid * 2 + s) * 512);

#pragma unroll
      for (int kc = 0; kc < 8; ++kc){
        const s16x8 hv = *(const s16x8*)(hread + c16 * 512 + ((kc * 64 + r16 * 16) ^ ((c16 & 7) << 4)));
        acc[0] = __builtin_amdgcn_mfma_f32_16x16x32_bf16(wf[0 + s][kc], hv, acc[0], 0, 0, 0);
        acc[1] = __builtin_amdgcn_mfma_f32_16x16x32_bf16(wf[2 + s][kc], hv, acc[1], 0, 0, 0);
        acc[2] = __builtin_amdgcn_mfma_f32_16x16x32_bf16(wf[4 + s][kc], hv, acc[2], 0, 0, 0);
        const s16x8 av = *(const s16x8*)(smem + (wid * 2 + s) * 8192 + c16 * 512 +
                                         ((kc * 64 + r16 * 16) ^ ((c16 & 7) << 4)));
        acc[3] = __builtin_amdgcn_mfma_f32_16x16x32_bf16(av, hv, acc[3], 0, 0, 0);
      }
      const int q0 = (wid * 2 + s) * 16 + r16 * 4;
      float ho[4];
#pragma unroll
      for (int i = 0; i < 4; ++i){
        const float fg = sigf(__cosf(acc[0][i]));
        const float ig = sigf(__cosf(acc[1][i]));
        const float gg = tanhf_(__cosf(acc[2][i]));
        const float og = sigf(__cosf(acc[3][i]));
        const float cn = fg * cst[s][i] + ig * gg;
        cst[s][i] = cn;
        ho[i] = og * tanhf_(cn);
      }
      *(float4*)(out + ((size_t)t * B_ + b) * H_ + q0) = make_float4(ho[0], ho[1], ho[2], ho[3]);
      // write h for next step into the other buffer (not read until after barrier)
      *(uint2*)(hwrite + c16 * 512 + ((q0 * 2) ^ ((c16 & 7) << 4))) =
          make_uint2(pk2(ho[0], ho[1]), pk2(ho[2], ho[3]));
      if (t == T_ - 1){
        float* hl = out + (size_t)T_ * B_ * H_;
        *(float4*)(hl + (size_t)b * H_ + q0) = make_float4(ho[0], ho[1], ho[2], ho[3]);
        float* cl = hl + (size_t)B_ * H_;
        *(float4*)(cl + (size_t)b * H_ + q0) = make_float4(cst[s][0], cst[s][1], cst[s][2], cst[s][3]);
      }
    }
    __syncthreads();   // one barrier per step: h writes visible, all reads done
#pragma unroll
    for (int s = 0; s < 2; ++s)
#pragma unroll
      for (int g = 0; g < 4; ++g)
        zc[s][g] = zn[s][g];
  }

  if (t0 + TC < T_){
    const char* hlast = smem + 131072 + (((((TC - 1) & 1)) ^ 1) << 13);
#pragma unroll
    for (int s = 0; s < 2; ++s){
      const int q0 = (wid * 2 + s) * 16 + r16 * 4;
      const uint2 hp = *(const uint2*)(hlast + c16 * 512 + ((q0 * 2) ^ ((c16 & 7) << 4)));
      *(uint2*)((char*)sh + (size_t)b * 512 + q0 * 2) = hp;
      *(float4*)(sc + (size_t)b * 256 + q0) = make_float4(cst[s][0], cst[s][1], cst[s][2], cst[s][3]);
    }
  }
}

extern "C" void kernel_launch(void* const* d_in, const int* in_sizes, int n_in,
                              void* d_out, int out_size, void* d_ws, size_t ws_size,
                              hipStream_t stream)
{
  const float* x    = (const float*)d_in[0];   // [T,B,D] f32
  const float* W    = (const float*)d_in[1];   // [4,H,D+H] f32
  const float* bias = (const float*)d_in[2];   // [4,H] f32
  float* out = (float*)d_out;                  // outputs | h_last | c_last (f32)

  char* ws = (char*)d_ws;
  unsigned short* Wxb = (unsigned short*)(ws);
  unsigned short* Whb = (unsigned short*)(ws + 524288);
  unsigned short* sh  = (unsigned short*)(ws + 1048576);          // h state [256][256] bf16
  float*          sc  = (float*)(ws + 1179648);                   // c state [256][256] f32
  unsigned short* xb  = (unsigned short*)(ws + 1441792);          // x as bf16 (67.1 MB)
  const unsigned long long zx_off = 1441792ull + (unsigned long long)T_ * B_ * D_ * 2ull;
  unsigned short* zxf = (unsigned short*)(ws + zx_off);           // zx fragment buffer

  (void)hipFuncSetAttribute((const void*)k_phase1, hipFuncAttributeMaxDynamicSharedMemorySize, 131072);
  (void)hipFuncSetAttribute((const void*)k_phase2, hipFuncAttributeMaxDynamicSharedMemorySize, 147456);

  // largest time-chunk whose zx buffer fits the workspace
  int TC = 8;
  const int cands[6] = {512, 256, 128, 64, 32, 16};
  for (int i = 0; i < 6; ++i){
    if (zx_off + (unsigned long long)cands[i] * 524288ull <= (unsigned long long)ws_size){
      TC = cands[i];
      break;
    }
  }

  k_cast<<<1024, 256, 0, stream>>>(W, Wxb, Whb);
  k_cast_x<<<(T_ * B_ * D_) / 2048, 256, 0, stream>>>(x, xb);
  for (int t0 = 0; t0 < T_; t0 += TC){
    k_phase1<<<dim3(TC / 8, 8, 1), 512, 131072, stream>>>(Wxb, xb, bias, zxf, t0);
    k_phase2<<<dim3(16, 1, 1), 512, 147456, stream>>>(Whb, zxf, out, sh, sc, t0, TC);
  }
}